// Round 4
// baseline (440.138 us; speedup 1.0000x reference)
//
#include <hip/hip_runtime.h>
#include <math.h>

// SubsetOperator: K=16 rounds of relaxed top-k (Gumbel softmax subset).
// B=2048 rows, N=16384 cols, fp32. One block (256 threads, 4 waves) per row.
//
// Exp-domain identity: s += log(max(1-oh,EPS)); softmax(s)  ==  e *= (1-oh).
// Inner loop: t = e*inv; khot += t; e = fmaf(-t,e,e); z += e  (4 VALU ops).
//
// R4 structure change vs R3: latency-bound (VALUBusy 40%, HBM 24%).
// 256 threads x EPT=64 -> 4x compute per barrier per wave; 4-wave barrier;
// 4-partial cross-wave reduce (broadcast + 2 shfl); 3 blocks/CU resident
// (launch_bounds(256,3), VGPR cap 170, state=128) so 3 independent blocks
// fill each block's ~1000-cy serial reduce+barrier window.

#define N_COLS   16384
#define K_ITERS  16
#define NTHREADS 256
#define EPT      (N_COLS / NTHREADS)   // 64 elements per thread
#define V4       (EPT / 4)             // 16 float4 chunks per thread

__global__ __launch_bounds__(NTHREADS, 3)
void subset_topk_kernel(const float* __restrict__ scores,
                        const float* __restrict__ g,
                        float* __restrict__ out)
{
    __shared__ float red[2][4];         // per-wave partials, double-buffered

    const int tid  = threadIdx.x;
    const int lane = tid & 63;
    const int wid  = tid >> 6;          // 4 waves per block
    const size_t base = (size_t)blockIdx.x * N_COLS;

    const float4* s4 = (const float4*)(scores + base);
    const float4* g4 = (const float4*)(g + base);
    float4*       o4 = (float4*)(out + base);

    float e[EPT], khot[EPT];

    // Load (interleaved float4 for coalescing), straight to exp-domain.
    float z0 = 0.f, z1 = 0.f, z2 = 0.f, z3 = 0.f;
    #pragma unroll
    for (int j = 0; j < V4; ++j) {
        float4 a = s4[j * NTHREADS + tid];
        float4 b = g4[j * NTHREADS + tid];
        float e0 = __expf(a.x + b.x);
        float e1 = __expf(a.y + b.y);
        float e2 = __expf(a.z + b.z);
        float e3 = __expf(a.w + b.w);
        e[j*4+0] = e0; e[j*4+1] = e1; e[j*4+2] = e2; e[j*4+3] = e3;
        z0 += e0; z1 += e1; z2 += e2; z3 += e3;
        khot[j*4+0] = 0.f; khot[j*4+1] = 0.f;
        khot[j*4+2] = 0.f; khot[j*4+3] = 0.f;
    }
    float zloc = (z0 + z1) + (z2 + z3);

    #pragma unroll 1
    for (int it = 0; it < K_ITERS; ++it) {
        // ---- wave-local sum (6-level xor shuffle) ----
        float z = zloc;
        #pragma unroll
        for (int o = 32; o > 0; o >>= 1) z += __shfl_xor(z, o, 64);
        if (lane == 0) red[it & 1][wid] = z;
        __syncthreads();

        // ---- cross-wave: lane l reads partial (l&3) [broadcast, no conflict],
        //      2-step xor-shuffle sums the 4 partials ----
        float v = red[it & 1][lane & 3];
        v += __shfl_xor(v, 1, 64);
        v += __shfl_xor(v, 2, 64);

        const float inv = __builtin_amdgcn_rcpf(v);

        // ---- 4-op inner loop, 4 independent z-accumulators ----
        z0 = 0.f; z1 = 0.f; z2 = 0.f; z3 = 0.f;
        #pragma unroll
        for (int j = 0; j < EPT; j += 4) {
            float t0 = e[j+0] * inv; khot[j+0] += t0;
            float n0 = fmaf(-t0, e[j+0], e[j+0]); e[j+0] = n0; z0 += n0;
            float t1 = e[j+1] * inv; khot[j+1] += t1;
            float n1 = fmaf(-t1, e[j+1], e[j+1]); e[j+1] = n1; z1 += n1;
            float t2 = e[j+2] * inv; khot[j+2] += t2;
            float n2 = fmaf(-t2, e[j+2], e[j+2]); e[j+2] = n2; z2 += n2;
            float t3 = e[j+3] * inv; khot[j+3] += t3;
            float n3 = fmaf(-t3, e[j+3], e[j+3]); e[j+3] = n3; z3 += n3;
        }
        zloc = (z0 + z1) + (z2 + z3);
    }

    // Store khot
    #pragma unroll
    for (int j = 0; j < V4; ++j) {
        float4 r;
        r.x = khot[j*4+0]; r.y = khot[j*4+1];
        r.z = khot[j*4+2]; r.w = khot[j*4+3];
        o4[j * NTHREADS + tid] = r;
    }
}

extern "C" void kernel_launch(void* const* d_in, const int* in_sizes, int n_in,
                              void* d_out, int out_size, void* d_ws, size_t ws_size,
                              hipStream_t stream) {
    const float* scores = (const float*)d_in[0];
    const float* g      = (const float*)d_in[1];
    float* out          = (float*)d_out;

    const int rows = in_sizes[0] / N_COLS;   // 2048
    subset_topk_kernel<<<rows, NTHREADS, 0, stream>>>(scores, g, out);
}

// Round 5
// 322.156 us; speedup vs baseline: 1.3662x; 1.3662x over previous
//
#include <hip/hip_runtime.h>
#include <math.h>

// SubsetOperator: K=16 rounds of relaxed top-k (Gumbel softmax subset).
// B=2048 rows, N=16384 cols, fp32. One block (512 threads, 8 waves) per row.
//
// Exp-domain identity: s += log(1-oh); softmax(s)  ==  e *= (1-oh); e/sum(e).
//
// R5: ITERATION PAIRING. One block reduction yields S1 = sum(e), S2 = sum(e^2);
// then Z1 = S1 and Z2 = sum(e*(1-e/Z1)) = S1 - S2/Z1, so TWO masking
// iterations run per barrier. 16 iters -> 8 reduce+barrier windows.
// Per element per pair (8 VALU ops, same 4/iter as R3):
//   t1=e*inv1; kh+=t1; e1=fmaf(-t1,e,e);
//   t2=e1*inv2; kh+=t2; e2=fmaf(-t2,e1,e1); s1+=e2; s2=fmaf(e2,e2,s2)
// EPT=32 @ 512 threads doubles compute per window; 8-wave barrier; 8-partial
// cross-wave reduce (broadcast + 3 shfl). R4 lesson: EPT=64 spills (VGPR=84,
// WRITE 497MB); EPT=32 state = 64 floats + temps ~ 85 VGPR, cap 256.

#define N_COLS   16384
#define K_ITERS  16
#define NPAIRS   (K_ITERS / 2)         // 8
#define NTHREADS 512
#define EPT      (N_COLS / NTHREADS)   // 32 elements per thread
#define V4       (EPT / 4)             // 8 float4 chunks per thread

__global__ __launch_bounds__(NTHREADS, 2)
void subset_topk_kernel(const float* __restrict__ scores,
                        const float* __restrict__ g,
                        float* __restrict__ out)
{
    __shared__ float2 red[2][8];        // per-wave (S1,S2) partials, dbuf

    const int tid  = threadIdx.x;
    const int lane = tid & 63;
    const int wid  = tid >> 6;          // 8 waves per block
    const size_t base = (size_t)blockIdx.x * N_COLS;

    const float4* s4 = (const float4*)(scores + base);
    const float4* g4 = (const float4*)(g + base);
    float4*       o4 = (float4*)(out + base);

    float e[EPT], khot[EPT];

    // Load (interleaved float4 for coalescing), straight to exp-domain,
    // accumulating S1 = sum e, S2 = sum e^2 with split chains.
    float s1a = 0.f, s1b = 0.f, s2a = 0.f, s2b = 0.f;
    #pragma unroll
    for (int j = 0; j < V4; ++j) {
        float4 a = s4[j * NTHREADS + tid];
        float4 b = g4[j * NTHREADS + tid];
        float e0 = __expf(a.x + b.x);
        float e1 = __expf(a.y + b.y);
        float e2 = __expf(a.z + b.z);
        float e3 = __expf(a.w + b.w);
        e[j*4+0] = e0; e[j*4+1] = e1; e[j*4+2] = e2; e[j*4+3] = e3;
        s1a += e0 + e1;  s1b += e2 + e3;
        s2a = fmaf(e0, e0, s2a); s2b = fmaf(e1, e1, s2b);
        s2a = fmaf(e2, e2, s2a); s2b = fmaf(e3, e3, s2b);
        khot[j*4+0] = 0.f; khot[j*4+1] = 0.f;
        khot[j*4+2] = 0.f; khot[j*4+3] = 0.f;
    }

    #pragma unroll 1
    for (int p = 0; p < NPAIRS; ++p) {
        // ---- wave-local sum of (S1, S2): 6-level xor shuffle, two streams ----
        float za = s1a + s1b;
        float zb = s2a + s2b;
        #pragma unroll
        for (int o = 32; o > 0; o >>= 1) {
            za += __shfl_xor(za, o, 64);
            zb += __shfl_xor(zb, o, 64);
        }
        if (lane == 0) red[p & 1][wid] = make_float2(za, zb);
        __syncthreads();

        // ---- cross-wave: lane l reads partial (l&7) [conflict-free broadcast],
        //      3-step xor-shuffle sums the 8 partials ----
        float2 v = red[p & 1][lane & 7];
        float va = v.x, vb = v.y;
        #pragma unroll
        for (int o = 1; o < 8; o <<= 1) {
            va += __shfl_xor(va, o, 64);
            vb += __shfl_xor(vb, o, 64);
        }

        const float Z1   = va;
        const float inv1 = __builtin_amdgcn_rcpf(Z1);
        const float Z2   = fmaf(-vb, inv1, Z1);     // S1 - S2/Z1
        const float inv2 = __builtin_amdgcn_rcpf(Z2);

        // ---- two masking iterations, fully in registers ----
        s1a = 0.f; s1b = 0.f; s2a = 0.f; s2b = 0.f;
        #pragma unroll
        for (int j = 0; j < EPT; j += 2) {
            float x0 = e[j+0];
            float t0 = x0 * inv1;
            float k0 = khot[j+0] + t0;
            float y0 = fmaf(-t0, x0, x0);
            float u0 = y0 * inv2;
            khot[j+0] = k0 + u0;
            float w0 = fmaf(-u0, y0, y0);
            e[j+0] = w0;
            s1a += w0; s2a = fmaf(w0, w0, s2a);

            float x1 = e[j+1];
            float t1 = x1 * inv1;
            float k1 = khot[j+1] + t1;
            float y1 = fmaf(-t1, x1, x1);
            float u1 = y1 * inv2;
            khot[j+1] = k1 + u1;
            float w1 = fmaf(-u1, y1, y1);
            e[j+1] = w1;
            s1b += w1; s2b = fmaf(w1, w1, s2b);
        }
    }

    // Store khot
    #pragma unroll
    for (int j = 0; j < V4; ++j) {
        float4 r;
        r.x = khot[j*4+0]; r.y = khot[j*4+1];
        r.z = khot[j*4+2]; r.w = khot[j*4+3];
        o4[j * NTHREADS + tid] = r;
    }
}

extern "C" void kernel_launch(void* const* d_in, const int* in_sizes, int n_in,
                              void* d_out, int out_size, void* d_ws, size_t ws_size,
                              hipStream_t stream) {
    const float* scores = (const float*)d_in[0];
    const float* g      = (const float*)d_in[1];
    float* out          = (float*)d_out;

    const int rows = in_sizes[0] / N_COLS;   // 2048
    subset_topk_kernel<<<rows, NTHREADS, 0, stream>>>(scores, g, out);
}